// Round 10
// baseline (880.587 us; speedup 1.0000x reference)
//
#include <hip/hip_runtime.h>

#define NBATCH 2
#define SEQ 2048
#define EMBED 1024
#define HEADS 16
#define HDIM 64

typedef _Float16 h16x8 __attribute__((ext_vector_type(8)));
typedef _Float16 h16x4 __attribute__((ext_vector_type(4)));
typedef float f32x4 __attribute__((ext_vector_type(4)));
typedef unsigned long long u64;

__device__ __forceinline__ h16x8 f8h(const float* p) {
    const float4 a = *(const float4*)p;
    const float4 b = *(const float4*)(p + 4);
    h16x8 r;
    r[0] = (_Float16)a.x; r[1] = (_Float16)a.y;
    r[2] = (_Float16)a.z; r[3] = (_Float16)a.w;
    r[4] = (_Float16)b.x; r[5] = (_Float16)b.y;
    r[6] = (_Float16)b.z; r[7] = (_Float16)b.w;
    return r;
}

// ---------------- mask int32 -> bit-packed u64 -------------------------------
__global__ __launch_bounds__(256) void maskpack(const int* __restrict__ m,
                                                u64* __restrict__ mb)
{
    const size_t i = (size_t)blockIdx.x * 256 + threadIdx.x;
    const u64 b = __ballot(m[i] != 0);
    if ((threadIdx.x & 63) == 0) mb[i >> 6] = b;
}

// ---------------- f32 -> f16 bulk convert (Wo) -------------------------------
__global__ __launch_bounds__(256) void cvt16(const float* __restrict__ in,
                                             _Float16* __restrict__ out, int n)
{
    const int i = (blockIdx.x * 256 + threadIdx.x) * 4;
    if (i < n) {
        const float4 v = *(const float4*)(in + i);
        h16x4 o;
        o[0] = (_Float16)v.x; o[1] = (_Float16)v.y;
        o[2] = (_Float16)v.z; o[3] = (_Float16)v.w;
        *(h16x4*)(out + i) = o;
    }
}

// ---------------- per-head K/V projection ------------------------------------
__global__ __launch_bounds__(256) void proj_kernel(
    const float* __restrict__ x, const float* __restrict__ W,
    const float* __restrict__ bias, _Float16* __restrict__ out, int transpose)
{
    const int wv = threadIdx.x >> 6;
    const int lane = threadIdx.x & 63;
    const int lr = lane & 15, lg = lane >> 4;
    const int nh = blockIdx.y, n = nh >> 4, h = nh & 15;
    const int lbase = blockIdx.x * 64 + wv * 16;

    const float* xrow = x + ((size_t)(n * SEQ + lbase + lr)) * EMBED + h * HDIM;
    const h16x8 a0 = f8h(xrow + lg * 8);
    const h16x8 a1 = f8h(xrow + 32 + lg * 8);

#pragma unroll
    for (int eb = 0; eb < 4; ++eb) {
        const float* wrow = W + (eb * 16 + lr) * HDIM;
        const h16x8 b0 = f8h(wrow + lg * 8);
        const h16x8 b1 = f8h(wrow + 32 + lg * 8);
        f32x4 c = {0.f, 0.f, 0.f, 0.f};
        c = __builtin_amdgcn_mfma_f32_16x16x32_f16(a0, b0, c, 0, 0, 0);
        c = __builtin_amdgcn_mfma_f32_16x16x32_f16(a1, b1, c, 0, 0, 0);
        const int col = eb * 16 + lr;
        const float bv = bias[col];
        if (!transpose) {
#pragma unroll
            for (int r = 0; r < 4; ++r) {
                const int row = lbase + lg * 4 + r;
                out[((size_t)nh * SEQ + row) * HDIM + col] = (_Float16)(c[r] + bv);
            }
        } else {
#pragma unroll
            for (int r = 0; r < 4; ++r) {
                const int row = lbase + lg * 4 + r;
                out[((size_t)nh * HDIM + col) * SEQ + row] = (_Float16)(c[r] + bv);
            }
        }
    }
}

// ---------------- attention: split-K, defer-max, 1 fence/iter ----------------
__global__ __launch_bounds__(256, 8) void attn_kernel(
    const float* __restrict__ xq, const float* __restrict__ Wq,
    const float* __restrict__ bq,
    const _Float16* __restrict__ Kp, const _Float16* __restrict__ Vt,
    const u64* __restrict__ mbits, _Float16* __restrict__ Xo,
    _Float16* __restrict__ pO, float2* __restrict__ pML, int nsplit)
{
    __shared__ __align__(16) _Float16 qlds[4][16 * 64];
    __shared__ __align__(16) _Float16 plds[4][16 * 64];
    const int wv = threadIdx.x >> 6;
    const int lane = threadIdx.x & 63;
    const int lr = lane & 15, lg = lane >> 4;

    // XCD-chunked swizzle over 1024*nsplit blocks
    const int bid = blockIdx.x;
    const int sbid = (bid & 7) * (128 * nsplit) + (bid >> 3);
    const int half = sbid % nsplit;
    const int qtnh = sbid / nsplit;          // nh*32 + qt
    const int qt = qtnh & 31, nh = qtnh >> 5;
    const int n = nh >> 4, h = nh & 15;
    const int qbase = qt * 64 + wv * 16;
    const int klen = SEQ / nsplit;
    const int kbeg = half * klen;

    _Float16* qb_ = qlds[wv];
    _Float16* pb_ = plds[wv];

    // ---- fused Q projection -> swizzled qlds -> A-frags ----
    {
        const float* xrow = xq + ((size_t)(n * SEQ + qbase + lr)) * EMBED + h * HDIM;
        const h16x8 a0 = f8h(xrow + lg * 8);
        const h16x8 a1 = f8h(xrow + 32 + lg * 8);
#pragma unroll
        for (int eb = 0; eb < 4; ++eb) {
            const float* wrow = Wq + (eb * 16 + lr) * HDIM;
            const h16x8 b0 = f8h(wrow + lg * 8);
            const h16x8 b1 = f8h(wrow + 32 + lg * 8);
            f32x4 c = {0.f, 0.f, 0.f, 0.f};
            c = __builtin_amdgcn_mfma_f32_16x16x32_f16(a0, b0, c, 0, 0, 0);
            c = __builtin_amdgcn_mfma_f32_16x16x32_f16(a1, b1, c, 0, 0, 0);
            const int col = eb * 16 + lr;
            const float bv = bq[col];
#pragma unroll
            for (int r = 0; r < 4; ++r) {
                const int row = lg * 4 + r;
                qb_[(row * 64 + col) ^ ((row & 7) << 3)] = (_Float16)(c[r] + bv);
            }
        }
    }
    asm volatile("s_waitcnt lgkmcnt(0)" ::: "memory");
    __builtin_amdgcn_sched_barrier(0);
    const h16x8 aq0 = *(const h16x8*)(qb_ + ((lr * 64 + lg * 8) ^ ((lr & 7) << 3)));
    const h16x8 aq1 = *(const h16x8*)(qb_ + ((lr * 64 + 32 + lg * 8) ^ ((lr & 7) << 3)));

    const u64* mrow = mbits + (size_t)n * SEQ * (SEQ / 64);
    const _Float16* kbase = Kp + (size_t)nh * SEQ * HDIM;
    const _Float16* vbase = Vt + (size_t)nh * HDIM * SEQ;

    const float SCL   = 0.0450842200277801f;   // log2(e)/32
    const float NEGS2 = -1e20f * 0.0450842200277801f;
    const float THR2  = 11.5415603f;           // 8*log2(e)

    float m_[4], lsl[4];
    f32x4 o_[4];
#pragma unroll
    for (int r = 0; r < 4; ++r) { m_[r] = -3.0e38f; lsl[r] = 0.f; }
#pragma unroll
    for (int db = 0; db < 4; ++db) o_[db] = (f32x4){0.f, 0.f, 0.f, 0.f};

    for (int kb = kbeg; kb < kbeg + klen; kb += 64) {
        // V + mask loads issued early
        h16x8 vf0[4], vf1[4];
#pragma unroll
        for (int db = 0; db < 4; ++db) {
            const _Float16* vr = vbase + (size_t)(db * 16 + lr) * SEQ + kb;
            vf0[db] = *(const h16x8*)(vr + lg * 8);
            vf1[db] = *(const h16x8*)(vr + 32 + lg * 8);
        }
        u64 mw[4];
#pragma unroll
        for (int r = 0; r < 4; ++r)
            mw[r] = mrow[(size_t)(qbase + lg * 4 + r) * (SEQ / 64) + (kb >> 6)];

        // ---- scores ----
        f32x4 s[4];
#pragma unroll
        for (int sg = 0; sg < 4; ++sg) {
            const _Float16* kr = kbase + (size_t)(kb + sg * 16 + lr) * HDIM;
            f32x4 c = {0.f, 0.f, 0.f, 0.f};
            c = __builtin_amdgcn_mfma_f32_16x16x32_f16(aq0, *(const h16x8*)(kr + lg * 8), c, 0, 0, 0);
            c = __builtin_amdgcn_mfma_f32_16x16x32_f16(aq1, *(const h16x8*)(kr + 32 + lg * 8), c, 0, 0, 0);
            s[sg] = c;
        }

        // ---- mask (before scale) into exp2 domain; in-lane max ----
        float tml[4];
#pragma unroll
        for (int r = 0; r < 4; ++r) {
            float t = -3.0e38f;
#pragma unroll
            for (int sg = 0; sg < 4; ++sg) {
                const bool on = (mw[r] >> (sg * 16 + lr)) & 1ull;
                s[sg][r] = on ? s[sg][r] * SCL : NEGS2;
                t = fmaxf(t, s[sg][r]);
            }
            tml[r] = t;
        }

        // ---- defer-max ----
        const bool ok = (tml[0] <= m_[0] + THR2) & (tml[1] <= m_[1] + THR2) &
                        (tml[2] <= m_[2] + THR2) & (tml[3] <= m_[3] + THR2);
        if (!__all(ok)) {
            float tm[4];
#pragma unroll
            for (int r = 0; r < 4; ++r) tm[r] = tml[r];
#pragma unroll
            for (int off = 1; off < 16; off <<= 1)
#pragma unroll
                for (int r = 0; r < 4; ++r) tm[r] = fmaxf(tm[r], __shfl_xor(tm[r], off));
#pragma unroll
            for (int r = 0; r < 4; ++r) {
                const float mn = fmaxf(m_[r], tm[r]);
                const float sc = exp2f(m_[r] - mn);
                m_[r] = mn;
                lsl[r] *= sc;
#pragma unroll
                for (int db = 0; db < 4; ++db) o_[db][r] *= sc;
            }
        }

        // ---- P = 2^(s-m); per-lane ls partials; P -> swizzled LDS ----
#pragma unroll
        for (int sg = 0; sg < 4; ++sg)
#pragma unroll
            for (int r = 0; r < 4; ++r) {
                const float p = exp2f(s[sg][r] - m_[r]);
                lsl[r] += p;
                const int row = lg * 4 + r;
                pb_[(row * 64 + sg * 16 + lr) ^ ((row & 7) << 3)] = (_Float16)p;
            }

        asm volatile("s_waitcnt lgkmcnt(0)" ::: "memory");
        __builtin_amdgcn_sched_barrier(0);
        const h16x8 pa0 = *(const h16x8*)(pb_ + ((lr * 64 + lg * 8) ^ ((lr & 7) << 3)));
        const h16x8 pa1 = *(const h16x8*)(pb_ + ((lr * 64 + 32 + lg * 8) ^ ((lr & 7) << 3)));

#pragma unroll
        for (int db = 0; db < 4; ++db) {
            o_[db] = __builtin_amdgcn_mfma_f32_16x16x32_f16(pa0, vf0[db], o_[db], 0, 0, 0);
            o_[db] = __builtin_amdgcn_mfma_f32_16x16x32_f16(pa1, vf1[db], o_[db], 0, 0, 0);
        }
    }

    // ---- epilogue: one ls reduction; write final or partial ----
#pragma unroll
    for (int off = 1; off < 16; off <<= 1)
#pragma unroll
        for (int r = 0; r < 4; ++r) lsl[r] += __shfl_xor(lsl[r], off);

    if (nsplit == 1) {
#pragma unroll
        for (int r = 0; r < 4; ++r) {
            const float inv = 1.0f / lsl[r];
            const int qr = qbase + lg * 4 + r;
            _Float16* orow = Xo + ((size_t)n * SEQ + qr) * EMBED + h * HDIM;
#pragma unroll
            for (int db = 0; db < 4; ++db)
                orow[db * 16 + lr] = (_Float16)(o_[db][r] * inv);
        }
    } else {
        const int pid = sbid;   // nh*64 + qt*2 + half
#pragma unroll
        for (int r = 0; r < 4; ++r) {
            const float inv = 1.0f / lsl[r];
            const int row = wv * 16 + lg * 4 + r;
            _Float16* prow = pO + ((size_t)pid * 64 + row) * 64;
#pragma unroll
            for (int db = 0; db < 4; ++db)
                prow[db * 16 + lr] = (_Float16)(o_[db][r] * inv);
            if (lr == 0) pML[(size_t)pid * 64 + row] = make_float2(m_[r], lsl[r]);
        }
    }
}

// ---------------- split-K combine: Xh = merge(pO half0, half1) ---------------
__global__ __launch_bounds__(256) void combine_kernel(
    const _Float16* __restrict__ pO, const float2* __restrict__ pML,
    _Float16* __restrict__ Xh)
{
    const int b = blockIdx.x;                 // nh*32 + qt
    const int nh = b >> 5, qt = b & 31;
    const int n = nh >> 4, h = nh & 15;
    const int row = threadIdx.x >> 2, dg = threadIdx.x & 3;
    const int pid0 = b * 2, pid1 = pid0 + 1;

    const float2 ml1 = pML[(size_t)pid0 * 64 + row];
    const float2 ml2 = pML[(size_t)pid1 * 64 + row];
    const float m = fmaxf(ml1.x, ml2.x);
    const float w1 = ml1.y * exp2f(ml1.x - m);
    const float w2 = ml2.y * exp2f(ml2.x - m);
    const float inv = 1.0f / (w1 + w2);
    const float a1 = w1 * inv, a2 = w2 * inv;

    const _Float16* p1 = pO + ((size_t)pid0 * 64 + row) * 64 + dg * 16;
    const _Float16* p2 = pO + ((size_t)pid1 * 64 + row) * 64 + dg * 16;
    _Float16* xr = Xh + ((size_t)n * SEQ + qt * 64 + row) * EMBED + h * HDIM + dg * 16;
#pragma unroll
    for (int j = 0; j < 16; ++j)
        xr[j] = (_Float16)(a1 * (float)p1[j] + a2 * (float)p2[j]);
}

// ---------------- output projection: 64x128 tile, LDS-staged B ---------------
__global__ __launch_bounds__(256, 2) void outproj_mfma(
    const _Float16* __restrict__ X, const _Float16* __restrict__ Wo16,
    const float* __restrict__ bo, float* __restrict__ out)
{
    __shared__ __align__(16) _Float16 Bs[128 * 64];   // [col][k], XOR-swizzled
    const int wv = threadIdx.x >> 6;
    const int lane = threadIdx.x & 63;
    const int lr = lane & 15, lg = lane >> 4;
    const int rbase = blockIdx.y * 64;
    const int cbase = blockIdx.x * 128;

    f32x4 acc[8];
#pragma unroll
    for (int cb = 0; cb < 8; ++cb) acc[cb] = (f32x4){0.f, 0.f, 0.f, 0.f};

    const _Float16* xrow = X + (size_t)(rbase + wv * 16 + lr) * EMBED;
    const int sc_ = threadIdx.x >> 1, skk = (threadIdx.x & 1) * 32;
    const _Float16* ssrc = Wo16 + (size_t)(cbase + sc_) * EMBED + skk;
    _Float16* sdst = Bs + sc_ * 64;
    const int ssw = (sc_ & 7) << 3;

    for (int k0 = 0; k0 < EMBED; k0 += 64) {
        __syncthreads();
#pragma unroll
        for (int j = 0; j < 4; ++j)
            *(h16x8*)(sdst + ((skk + j * 8) ^ ssw)) = *(const h16x8*)(ssrc + k0 + j * 8);
        __syncthreads();
#pragma unroll
        for (int kk2 = 0; kk2 < 2; ++kk2) {
            const h16x8 a = *(const h16x8*)(xrow + k0 + kk2 * 32 + lg * 8);
#pragma unroll
            for (int cb = 0; cb < 8; ++cb) {
                const int c = cb * 16 + lr;
                const h16x8 b = *(const h16x8*)(Bs + c * 64 + ((kk2 * 32 + lg * 8) ^ ((c & 7) << 3)));
                acc[cb] = __builtin_amdgcn_mfma_f32_16x16x32_f16(a, b, acc[cb], 0, 0, 0);
            }
        }
    }
#pragma unroll
    for (int cb = 0; cb < 8; ++cb) {
        const int col = cbase + cb * 16 + lr;
        const float bv = bo[col];
#pragma unroll
        for (int r = 0; r < 4; ++r) {
            const int row = rbase + wv * 16 + lg * 4 + r;
            out[(size_t)row * EMBED + col] = acc[cb][r] + bv;
        }
    }
}

extern "C" void kernel_launch(void* const* d_in, const int* in_sizes, int n_in,
                              void* d_out, int out_size, void* d_ws, size_t ws_size,
                              hipStream_t stream)
{
    const float* q    = (const float*)d_in[0];
    const float* k    = (const float*)d_in[1];
    const float* v    = (const float*)d_in[2];
    const int*  mask  = (const int*)d_in[3];
    const float* Wq   = (const float*)d_in[4];
    const float* bq   = (const float*)d_in[5];
    const float* Wk   = (const float*)d_in[6];
    const float* bk   = (const float*)d_in[7];
    const float* Wv   = (const float*)d_in[8];
    const float* bv   = (const float*)d_in[9];
    const float* Wo   = (const float*)d_in[10];
    const float* bo   = (const float*)d_in[11];

    const size_t per = (size_t)NBATCH * HEADS * SEQ * HDIM;       // 4.19M elems
    const size_t nmask = (size_t)NBATCH * SEQ * SEQ;
    u64*      mbits = (u64*)d_ws;                                 // 1.05 MB
    _Float16* Kp    = (_Float16*)(mbits + nmask / 64);            // 8.39 MB
    _Float16* Vt    = Kp + per;                                   // 8.39 MB
    _Float16* Xh    = Vt + per;                                   // 8.39 MB
    _Float16* Wo16  = Xh + per;                                   // 2.10 MB
    _Float16* pO    = Wo16 + (size_t)EMBED * EMBED;               // 16.78 MB
    float2*   pML   = (float2*)(pO + (size_t)2048 * 64 * 64);     // 1.05 MB
    const size_t need = 46137344;                                  // 44 MiB
    const int nsplit = (ws_size >= need) ? 2 : 1;

    maskpack<<<(int)(nmask / 256), 256, 0, stream>>>(mask, mbits);
    cvt16<<<EMBED * EMBED / 1024, 256, 0, stream>>>(Wo, Wo16, EMBED * EMBED);
    const dim3 pgrid(SEQ / 64, NBATCH * HEADS);
    proj_kernel<<<pgrid, 256, 0, stream>>>(k, Wk, bk, Kp, 0);
    proj_kernel<<<pgrid, 256, 0, stream>>>(v, Wv, bv, Vt, 1);
    attn_kernel<<<1024 * nsplit, 256, 0, stream>>>(q, Wq, bq, Kp, Vt, mbits, Xh, pO, pML, nsplit);
    if (nsplit == 2)
        combine_kernel<<<1024, 256, 0, stream>>>(pO, pML, Xh);
    outproj_mfma<<<dim3(EMBED / 128, NBATCH * SEQ / 64), 256, 0, stream>>>(Xh, Wo16, bo, (float*)d_out);
}